// Round 10
// baseline (203.721 us; speedup 1.0000x reference)
//
#include <hip/hip_runtime.h>
#include <stdint.h>
#include <stddef.h>

#define N_SENT 100000
#define N_TYPE 10000
#define NEDGE  640000
#define NROWS  (N_SENT + N_TYPE)
#define HB     128              // histogram chunks; 128 * 5000 == NEDGE
#define HCHUNK (NEDGE / HB)

__device__ __forceinline__ float bf2f(uint32_t lo16) {
    return __builtin_bit_cast(float, lo16 << 16);
}
__device__ __forceinline__ uint32_t f2bf(float f) {
    uint32_t u = __builtin_bit_cast(uint32_t, f);
    return (u + 0x7fffu + ((u >> 16) & 1u)) >> 16;
}
// bf16 pairs have bf16-sane exponents in the low halfword; f32 low halfwords are
// mantissa bits (uniform). One broadcast load + ballot, wave-uniform result.
__device__ __forceinline__ bool detect_bf16(const uint32_t* __restrict__ h) {
    uint32_t u = h[threadIdx.x & 63];
    uint32_t e_lo = (u >> 7) & 0xffu;
    int ok = (e_lo >= 100u && e_lo <= 140u) ? 1 : 0;
    unsigned long long m = __ballot(ok);
    return __popcll(m) >= 48;
}

// ---- fused: per-row scores (16 rows/wave butterfly GEMV) + per-chunk LDS dst-histogram ----
#define SCORE_BLOCKS ((NROWS + 63) / 64)   // 1719

__global__ __launch_bounds__(256) void scores_count_k(const void* __restrict__ h_sent,
                                                      const void* __restrict__ h_type,
                                                      const void* __restrict__ attn_w,
                                                      const int* __restrict__ dst,
                                                      float* __restrict__ s_src,
                                                      float* __restrict__ s_dst,
                                                      uint32_t* __restrict__ count2) {
    __shared__ uint32_t hist[N_TYPE];   // 40 KB (count blocks only)
    int b = blockIdx.x;
    if (b < SCORE_BLOCKS) {
        int lane = threadIdx.x & 63;
        int r0   = (b * 4 + (int)(threadIdx.x >> 6)) * 16;
        bool isbf = detect_bf16((const uint32_t*)h_sent);
        float v[16];
        if (isbf) {
            uint32_t wv_s = ((const uint32_t*)attn_w)[lane];
            uint32_t wv_t = ((const uint32_t*)attn_w)[64 + lane];
            float ws0 = bf2f(wv_s & 0xffffu), ws1 = bf2f(wv_s >> 16);
            float wt0 = bf2f(wv_t & 0xffffu), wt1 = bf2f(wv_t >> 16);
#pragma unroll
            for (int i = 0; i < 16; i++) {
                int g = r0 + i;
                if (g >= NROWS) { v[i] = 0.0f; continue; }
                bool isSrc = g < N_SENT;
                const uint32_t* hp = isSrc
                    ? (const uint32_t*)h_sent + (size_t)g * 64
                    : (const uint32_t*)h_type + (size_t)(g - N_SENT) * 64;
                uint32_t hv = hp[lane];
                v[i] = isSrc ? (bf2f(hv & 0xffffu) * ws0 + bf2f(hv >> 16) * ws1)
                             : (bf2f(hv & 0xffffu) * wt0 + bf2f(hv >> 16) * wt1);
            }
        } else {
            float2 wv_s = ((const float2*)attn_w)[lane];
            float2 wv_t = ((const float2*)attn_w)[64 + lane];
#pragma unroll
            for (int i = 0; i < 16; i++) {
                int g = r0 + i;
                if (g >= NROWS) { v[i] = 0.0f; continue; }
                bool isSrc = g < N_SENT;
                const float2* hp = isSrc
                    ? (const float2*)h_sent + (size_t)g * 64
                    : (const float2*)h_type + (size_t)(g - N_SENT) * 64;
                float2 hv = hp[lane];
                v[i] = isSrc ? (hv.x * wv_s.x + hv.y * wv_s.y)
                             : (hv.x * wv_t.x + hv.y * wv_t.y);
            }
        }
        // fold 16 rows -> 1 value/lane (row = lane&15): merge d=1,2,4,8 then butterfly
        int b0 = lane & 1, b1 = (lane >> 1) & 1, b2 = (lane >> 2) & 1, b3 = (lane >> 3) & 1;
        float w_[8];
#pragma unroll
        for (int i = 0; i < 8; i++) {
            float keep = b0 ? v[2 * i + 1] : v[2 * i];
            float send = b0 ? v[2 * i]     : v[2 * i + 1];
            w_[i] = keep + __shfl_xor(send, 1, 64);
        }
        float x_[4];
#pragma unroll
        for (int i = 0; i < 4; i++) {
            float keep = b1 ? w_[2 * i + 1] : w_[2 * i];
            float send = b1 ? w_[2 * i]     : w_[2 * i + 1];
            x_[i] = keep + __shfl_xor(send, 2, 64);
        }
        float y_[2];
#pragma unroll
        for (int i = 0; i < 2; i++) {
            float keep = b2 ? x_[2 * i + 1] : x_[2 * i];
            float send = b2 ? x_[2 * i]     : x_[2 * i + 1];
            y_[i] = keep + __shfl_xor(send, 4, 64);
        }
        float z;
        {
            float keep = b3 ? y_[1] : y_[0];
            float send = b3 ? y_[0] : y_[1];
            z = keep + __shfl_xor(send, 8, 64);
        }
        z += __shfl_xor(z, 16, 64);
        z += __shfl_xor(z, 32, 64);
        if (lane < 16) {
            int g = r0 + lane;
            if (g < NROWS) {
                if (g < N_SENT) s_src[g] = z;
                else            s_dst[g - N_SENT] = z;
            }
        }
    } else {
        int cb = b - SCORE_BLOCKS;           // [0, HB)
        int t  = threadIdx.x;
        for (int i = t; i < N_TYPE; i += 256) hist[i] = 0u;
        __syncthreads();
        int e0 = cb * HCHUNK;
        for (int i = t; i < HCHUNK; i += 256)
            atomicAdd(&hist[dst[e0 + i]], 1u);
        __syncthreads();
        uint32_t* row = count2 + (size_t)cb * N_TYPE;
        for (int i = t; i < N_TYPE; i += 256) row[i] = hist[i];
    }
}

// ---- column exclusive-scan over chunks: count2 -> base2 (in place), total[bin] ----
__global__ __launch_bounds__(256) void sumscan_k(uint32_t* __restrict__ count2,
                                                 uint32_t* __restrict__ total) {
    int b = blockIdx.x * 256 + threadIdx.x;
    if (b >= N_TYPE) return;
    uint32_t run = 0;
#pragma unroll 8
    for (int c = 0; c < HB; c++) {
        uint32_t* p = count2 + (size_t)c * N_TYPE + b;
        uint32_t v = *p;
        *p = run;
        run += v;
    }
    total[b] = run;
}

// ---- single-block exclusive scan of totals -> offsets[N_TYPE+1] ----
__global__ __launch_bounds__(1024) void scan_k(const uint32_t* __restrict__ total,
                                               uint32_t* __restrict__ offsets) {
    const int CH = 10;
    int t = threadIdx.x, lane = t & 63, wv = t >> 6;
    int base = t * CH;
    uint32_t local[CH];
    uint32_t tsum = 0;
#pragma unroll
    for (int i = 0; i < CH; i++) {
        int idx = base + i;
        uint32_t c = (idx < N_TYPE) ? total[idx] : 0u;
        local[i] = c;
        tsum += c;
    }
    uint32_t orig = tsum;
#pragma unroll
    for (int off = 1; off < 64; off <<= 1) {
        uint32_t v = __shfl_up(tsum, off, 64);
        if (lane >= off) tsum += v;
    }
    __shared__ uint32_t wsum[16];
    if (lane == 63) wsum[wv] = tsum;
    __syncthreads();
    if (wv == 0 && lane < 16) {
        uint32_t u = wsum[lane], o = u;
#pragma unroll
        for (int off = 1; off < 16; off <<= 1) {
            uint32_t v = __shfl_up(u, off, 64);
            if (lane >= off) u += v;
        }
        wsum[lane] = u - o;
    }
    __syncthreads();
    uint32_t run = wsum[wv] + tsum - orig;
#pragma unroll
    for (int i = 0; i < CH; i++) {
        int idx = base + i;
        if (idx < N_TYPE) {
            offsets[idx] = run;
            run += local[i];
        } else if (idx == N_TYPE) {
            offsets[idx] = run;   // == NEDGE
        }
    }
}

// ---- fill: LDS cursors from offsets+base2; scatter (src, w=exp(lrelu(score))) by dst ----
__global__ __launch_bounds__(256) void fill_k(const int* __restrict__ src,
                                              const int* __restrict__ dst,
                                              const float* __restrict__ s_src,
                                              const float* __restrict__ s_dst,
                                              const uint32_t* __restrict__ offsets,
                                              const uint32_t* __restrict__ base2,
                                              uint2* __restrict__ edata) {
    __shared__ uint32_t cur[N_TYPE];   // 40 KB
    int cb = blockIdx.x;
    int t  = threadIdx.x;
    const uint4* off4 = (const uint4*)offsets;                       // N_TYPE % 4 == 0
    const uint4* brow4 = (const uint4*)(base2 + (size_t)cb * N_TYPE);
    for (int i = t; i < N_TYPE / 4; i += 256) {
        uint4 o = off4[i], bq = brow4[i];
        cur[4 * i + 0] = o.x + bq.x;
        cur[4 * i + 1] = o.y + bq.y;
        cur[4 * i + 2] = o.z + bq.z;
        cur[4 * i + 3] = o.w + bq.w;
    }
    __syncthreads();
    int e0 = cb * HCHUNK;
    for (int i = t; i < HCHUNK; i += 256) {
        int e = e0 + i;
        int d = dst[e];
        int s = src[e];
        float v = s_src[s] + s_dst[d];
        v = v > 0.0f ? v : 0.01f * v;
        float w = __expf(v);                    // max-free softmax: |v| small, f32-safe
        uint32_t pos = atomicAdd(&cur[d], 1u);  // LDS-only atomic
        edata[pos] = make_uint2((uint32_t)s, __builtin_bit_cast(uint32_t, w));
    }
}

// ---- agg v4: one wave per dst, WIDE gathers.
//      bf16: uint4/lane, 16 lanes per 256B row -> 4 rows per load instruction.
//      f32 : float4/lane, 32 lanes per 512B row -> 2 rows per load instruction.
//      edata preloaded 32(16) edges with one load, distributed by shfl. ----
__global__ __launch_bounds__(256) void agg_k(const void* __restrict__ h_sent,
                                             const void* __restrict__ h_type,
                                             const uint32_t* __restrict__ offsets,
                                             const uint2* __restrict__ edata,
                                             void* __restrict__ out) {
    int lane = threadIdx.x & 63;
    int j = (blockIdx.x * 256 + (int)threadIdx.x) >> 6;
    if (j >= N_TYPE) return;
    bool isbf = detect_bf16((const uint32_t*)h_sent);
    uint32_t beg = offsets[j], end = offsets[j + 1];
    if (isbf) {
        int g = lane >> 4, p = lane & 15;          // 4 groups x 16 lanes
        if (beg == end) {                          // isolated: copy h_type row
            if (lane < 16)
                ((uint4*)out)[(size_t)j * 16 + p] = ((const uint4*)h_type)[(size_t)j * 16 + p];
            return;
        }
        const uint4* hp = (const uint4*)h_sent;    // row = 16 uint4
        float a[8] = {0, 0, 0, 0, 0, 0, 0, 0};
        float den = 0.0f;
        uint32_t k = beg;
        for (; k + 32 <= end; k += 32) {
            uint2 ed = edata[k + (lane & 31)];     // 32 edges in one load
#pragma unroll
            for (int i = 0; i < 8; i++) {
                int sl = 4 * i + g;
                uint32_t s = (uint32_t)__shfl((int)ed.x, sl, 64);
                float    w = __builtin_bit_cast(float, (uint32_t)__shfl((int)ed.y, sl, 64));
                uint4 gv = hp[(size_t)s * 16 + p];
                den += w;
                a[0] += w * bf2f(gv.x & 0xffffu); a[1] += w * bf2f(gv.x >> 16);
                a[2] += w * bf2f(gv.y & 0xffffu); a[3] += w * bf2f(gv.y >> 16);
                a[4] += w * bf2f(gv.z & 0xffffu); a[5] += w * bf2f(gv.z >> 16);
                a[6] += w * bf2f(gv.w & 0xffffu); a[7] += w * bf2f(gv.w >> 16);
            }
        }
        for (; k < end; k += 4) {                  // tail: 4 edges/iter, masked groups
            uint32_t idx = k + (uint32_t)g;
            bool valid = idx < end;
            uint2 ed = edata[valid ? idx : (end - 1)];
            float w = valid ? __builtin_bit_cast(float, ed.y) : 0.0f;
            uint4 gv = hp[(size_t)ed.x * 16 + p];
            den += w;
            a[0] += w * bf2f(gv.x & 0xffffu); a[1] += w * bf2f(gv.x >> 16);
            a[2] += w * bf2f(gv.y & 0xffffu); a[3] += w * bf2f(gv.y >> 16);
            a[4] += w * bf2f(gv.z & 0xffffu); a[5] += w * bf2f(gv.z >> 16);
            a[6] += w * bf2f(gv.w & 0xffffu); a[7] += w * bf2f(gv.w >> 16);
        }
        // merge the 4 groups (disjoint edge subsets, same dims per p)
#pragma unroll
        for (int i = 0; i < 8; i++) {
            a[i] += __shfl_xor(a[i], 16, 64);
            a[i] += __shfl_xor(a[i], 32, 64);
        }
        den += __shfl_xor(den, 16, 64);
        den += __shfl_xor(den, 32, 64);
        float inv = 1.0f / den;
        if (lane < 16) {
            uint4 o;
            o.x = f2bf(a[0] * inv) | (f2bf(a[1] * inv) << 16);
            o.y = f2bf(a[2] * inv) | (f2bf(a[3] * inv) << 16);
            o.z = f2bf(a[4] * inv) | (f2bf(a[5] * inv) << 16);
            o.w = f2bf(a[6] * inv) | (f2bf(a[7] * inv) << 16);
            ((uint4*)out)[(size_t)j * 16 + p] = o;
        }
    } else {
        int g = lane >> 5, p = lane & 31;          // 2 groups x 32 lanes
        if (beg == end) {
            if (lane < 32)
                ((float4*)out)[(size_t)j * 32 + p] = ((const float4*)h_type)[(size_t)j * 32 + p];
            return;
        }
        const float4* hp = (const float4*)h_sent;  // row = 32 float4
        float a0 = 0, a1 = 0, a2 = 0, a3 = 0, den = 0.0f;
        uint32_t k = beg;
        for (; k + 16 <= end; k += 16) {
            uint2 ed = edata[k + (lane & 15)];     // 16 edges in one load
#pragma unroll
            for (int i = 0; i < 8; i++) {
                int sl = 2 * i + g;
                uint32_t s = (uint32_t)__shfl((int)ed.x, sl, 64);
                float    w = __builtin_bit_cast(float, (uint32_t)__shfl((int)ed.y, sl, 64));
                float4 gv = hp[(size_t)s * 32 + p];
                den += w;
                a0 += w * gv.x; a1 += w * gv.y; a2 += w * gv.z; a3 += w * gv.w;
            }
        }
        for (; k < end; k += 2) {
            uint32_t idx = k + (uint32_t)g;
            bool valid = idx < end;
            uint2 ed = edata[valid ? idx : (end - 1)];
            float w = valid ? __builtin_bit_cast(float, ed.y) : 0.0f;
            float4 gv = hp[(size_t)ed.x * 32 + p];
            den += w;
            a0 += w * gv.x; a1 += w * gv.y; a2 += w * gv.z; a3 += w * gv.w;
        }
        a0 += __shfl_xor(a0, 32, 64);
        a1 += __shfl_xor(a1, 32, 64);
        a2 += __shfl_xor(a2, 32, 64);
        a3 += __shfl_xor(a3, 32, 64);
        den += __shfl_xor(den, 32, 64);
        float inv = 1.0f / den;
        if (lane < 32)
            ((float4*)out)[(size_t)j * 32 + p] = make_float4(a0 * inv, a1 * inv, a2 * inv, a3 * inv);
    }
}

static inline size_t align_up(size_t x) { return (x + 255) & ~(size_t)255; }

extern "C" void kernel_launch(void* const* d_in, const int* in_sizes, int n_in,
                              void* d_out, int out_size, void* d_ws, size_t ws_size,
                              hipStream_t stream) {
    const void* h_sent = d_in[0];
    const void* h_type = d_in[1];
    const void* attn_w = d_in[2];
    const int* src_idx = (const int*)d_in[3];
    const int* dst_idx = (const int*)d_in[4];

    char* w = (char*)d_ws;
    float*    s_src   = (float*)w;    w += align_up((size_t)N_SENT * 4);
    float*    s_dst   = (float*)w;    w += align_up((size_t)N_TYPE * 4);
    uint32_t* count2  = (uint32_t*)w; w += align_up((size_t)HB * N_TYPE * 4);   // 5.12 MB
    uint32_t* total   = (uint32_t*)w; w += align_up((size_t)N_TYPE * 4);
    uint32_t* offsets = (uint32_t*)w; w += align_up((size_t)(N_TYPE + 1) * 4);
    uint2*    edata   = (uint2*)w;    w += align_up((size_t)NEDGE * 8);         // 5.12 MB
    // total ~10.8 MB (harness ws_size >= 26.5 MB confirmed in r8)

    scores_count_k<<<SCORE_BLOCKS + HB, 256, 0, stream>>>(
        h_sent, h_type, attn_w, dst_idx, s_src, s_dst, count2);
    sumscan_k<<<(N_TYPE + 255) / 256, 256, 0, stream>>>(count2, total);
    scan_k<<<1, 1024, 0, stream>>>(total, offsets);
    fill_k<<<HB, 256, 0, stream>>>(src_idx, dst_idx, s_src, s_dst, offsets, count2, edata);
    agg_k<<<(N_TYPE + 3) / 4, 256, 0, stream>>>(h_sent, h_type, offsets, edata, d_out);
}